// Round 8
// baseline (126.860 us; speedup 1.0000x reference)
//
#include <hip/hip_runtime.h>

typedef __attribute__((ext_vector_type(8))) short short8;
typedef __attribute__((ext_vector_type(4))) float f32x4;

#define IN_DIM 256
#define OUT_DIM 256
#define NB 16                 // padded basis count (13 real + 3 zero)
#define KDIM (IN_DIM * NB)    // 4096
#define TM 32
#define TN 128
#define BK 64                 // 4 i-values per K-step (128 B per row)
#define STEPS 64              // full K per block (no split-K)
#define ABUF 4096             // bytes per A double-buffer half (TM*BK*2)
#define BTILE 16384           // bytes per B ring slot (TN*BK*2)

__device__ __forceinline__ unsigned short f2bf(float f) {
  union { float f; unsigned int u; } v; v.f = f;
  unsigned int r = v.u + 0x7fffu + ((v.u >> 16) & 1u);  // RNE
  return (unsigned short)(r >> 16);
}

// async global->LDS, 16 B per lane, linear wave dest (base + lane*16)
__device__ __forceinline__ void glds16(const void* g, void* l) {
  __builtin_amdgcn_global_load_lds((__attribute__((address_space(1))) const void*)g,
                                   (__attribute__((address_space(3))) void*)l, 16, 0, 0);
}

// branchless cubic B-spline row: 16 bf16 slots (packed into d[8] u32), 4 nonzeros at c..c+3
__device__ __forceinline__ void spline_row(float xv, unsigned* d) {
  float xc = fminf(fmaxf(xv, -1.0f), 1.0f - 1e-6f);
  float u = (xc + 1.0f) * 5.0f;            // h = 0.2
  int c = (int)u;
  c = c > 9 ? 9 : (c < 0 ? 0 : c);
  float tt = u - (float)c;
  float omt = 1.0f - tt;
  float t2 = tt * tt, t3 = t2 * tt;
  float b0 = omt * omt * omt * (1.0f / 6.0f);
  float b1 = (3.0f * t3 - 6.0f * t2 + 4.0f) * (1.0f / 6.0f);
  float b2 = (-3.0f * t3 + 3.0f * t2 + 3.0f * tt + 1.0f) * (1.0f / 6.0f);
  float b3 = t3 * (1.0f / 6.0f);
  unsigned h0 = f2bf(b0), h1 = f2bf(b1), h2 = f2bf(b2), h3 = f2bf(b3);
  const int a = c >> 1;
  const bool odd = (c & 1) != 0;
  unsigned p01 = h0 | (h1 << 16);
  unsigned p23 = h2 | (h3 << 16);
  unsigned A0 = odd ? (h0 << 16) : p01;
  unsigned A1 = odd ? (h1 | (h2 << 16)) : p23;
  unsigned A2 = odd ? h3 : 0u;
#pragma unroll
  for (int j = 0; j < 8; ++j) {
    unsigned v = (j == a) ? A0 : 0u;
    v = (j == a + 1) ? A1 : v;
    v = (j == a + 2) ? A2 : v;
    d[j] = v;
  }
}

// --- prep: BmT[o][i*16+n] = bf16( sum_e softmax(gating[i,o,:])[e] * coeff[e,n] )
// (no output zeroing: gemm does plain stores, no atomics)
__global__ __launch_bounds__(256) void kan_prep(const float* __restrict__ coeff,
                                                const float* __restrict__ gw,
                                                unsigned short* __restrict__ BmT) {
  __shared__ float csh[104];
  __shared__ unsigned short tile[16][256];   // [o_loc][il*16+n]
  const int t = threadIdx.x;
  if (t < 104) csh[t] = coeff[t];
  __syncthreads();
  const int otile = blockIdx.x, itile = blockIdx.y;
  const int il = t >> 4, ol = t & 15;
  const int i = itile * 16 + il;
  const int o = otile * 16 + ol;
  const float* g = gw + (size_t)(i * OUT_DIM + o) * 8;
  float4 g0 = *(const float4*)g;
  float4 g1 = *(const float4*)(g + 4);
  float ge[8] = {g0.x, g0.y, g0.z, g0.w, g1.x, g1.y, g1.z, g1.w};
  float mx = ge[0];
#pragma unroll
  for (int e = 1; e < 8; ++e) mx = fmaxf(mx, ge[e]);
  float p[8]; float s = 0.f;
#pragma unroll
  for (int e = 0; e < 8; ++e) { p[e] = __expf(ge[e] - mx); s += p[e]; }
  const float inv = 1.0f / s;
  unsigned short row[16];
#pragma unroll
  for (int n = 0; n < 13; ++n) {
    float w = 0.f;
#pragma unroll
    for (int e = 0; e < 8; ++e) w += p[e] * csh[e * 13 + n];
    row[n] = f2bf(w * inv);
  }
  row[13] = 0; row[14] = 0; row[15] = 0;
  int4* dst = (int4*)&tile[ol][il * 16];
  dst[0] = *(const int4*)&row[0];
  dst[1] = *(const int4*)&row[8];
  __syncthreads();
  const int oo = t >> 4, ck = t & 15;
  int4 v0 = *(const int4*)&tile[oo][ck * 16];
  int4 v1 = *(const int4*)&tile[oo][ck * 16 + 8];
  int4* out4 = (int4*)(BmT + (size_t)(otile * 16 + oo) * KDIM + itile * 256 + ck * 16);
  out4[0] = v0;
  out4[1] = v1;
}

// --- fused basis + GEMM with a COUNTED-vmcnt pipeline (T3/T4), DMA-only VMEM:
// TM=32 x TN=128, full K (64 steps of BK=64), grid 512 = 2 blocks/CU, no atomics.
// ALL vector-memory ops in the loop are global_load_lds DMAs (deterministic,
// wave-uniform counts; no asm register outputs -> no async-write hazards):
//   B tiles: ring-3 of 16 KB slots, DMA'd 2 steps ahead.
//   x:       ring-3 of 1 KB slots, DMA'd 3 steps ahead (all waves redundantly,
//            identical bytes -> benign), read back via plain ds_read.
// Per-wave queue entering step s: [T(s+1)(4), X(s+2)(1)]; step issues
// T(s+2)(4), X(s+3)(1); ONE pre-barrier s_waitcnt vmcnt(5) retires exactly
// T(s+1)+X(s+2). No vmcnt(0) in the loop: next tile's DMAs stay in flight
// across the raw barrier with a full step of slack. lgkmcnt(0)+sched_barrier(0)
// before each barrier covers the spline's A-tile ds_writes (rule 18).
// Tail stays count-uniform via clamped dummy DMAs into dead ring slots.
// LDS: A 8K + B 48K + X 3K = 59 KB -> 2 blocks/CU.
__global__ __launch_bounds__(256, 2) void kan_gemm(const float* __restrict__ x,
                                                   const unsigned short* __restrict__ BmT,
                                                   float* __restrict__ out) {
  __shared__ unsigned short Ash[2][TM * BK];   // 2 x 4096 B, swizzled [row][64k]
  __shared__ unsigned short Bsh[3][TN * BK];   // 3 x 16384 B ring, swizzled [o][64k]
  __shared__ float Xsh[3 * 256];               // 3 x 1024 B ring: slot u%3, row r floats 4r..4r+3

  const int t = threadIdx.x;
  const int lane = t & 63;
  const int wave = t >> 6;                     // 4 waves: 1 M x 4 N, each 32x32
  const int wn = wave;
  const int mb = blockIdx.x * TM;
  const int ob = blockIdx.y * TN;

  // A-stager mapping: threads 0..127 -> (row r, i-slot il)
  const int r = t & 31;
  const int il = (t >> 5) & 3;
  const bool astage = t < 128;
  char* const abase = (char*)&Ash[0][0] + r * 128;
  const int msw = r & 7;
  const int aw0 = ((2 * il + 0) ^ msw) << 4;   // swizzled byte slots for this eval
  const int aw1 = ((2 * il + 1) ^ msw) << 4;

  // x DMA source: lane l covers row (l&31), 16 B = 4 floats of step-group u at +4u
  const float* const xg = x + (size_t)(mb + (lane & 31)) * IN_DIM;

  // B DMA: call q covers LDS linear bytes q*4096 + t*16 of a ring slot
  //   row = q*32 + (t>>3); linear granule (t&7) holds global granule (t&7)^(row&7)
  const unsigned short* bgbase =
      BmT + (size_t)(ob + (t >> 3)) * KDIM + ((t & 7) ^ ((t >> 3) & 7)) * 8;

  f32x4 acc[2][2];
#pragma unroll
  for (int a = 0; a < 2; ++a)
#pragma unroll
    for (int b = 0; b < 2; ++b) acc[a][b] = (f32x4){0.f, 0.f, 0.f, 0.f};

  // swizzled fragment read offsets (kc=0); kc toggles via ^(kc<<6)
  int aoff[2], boff[2];
#pragma unroll
  for (int f = 0; f < 2; ++f) {
    const int ro = f * 16 + (lane & 15);
    aoff[f] = ro * 128 + (((lane >> 4) ^ (ro & 7)) << 4);
    const int bo = wn * 32 + f * 16 + (lane & 15);
    boff[f] = bo * 128 + (((lane >> 4) ^ (bo & 7)) << 4);
  }

  // ---- prologue: x0 plain load; DMA T0, X1, T1, X2; spline(x0)->A[0];
  // vmcnt(5) retires T0+X1 (leaves [T1(4), X2] in flight), lgkmcnt(0), barrier.
  {
    float x0v = 0.f;
    if (astage) x0v = x[(size_t)(mb + r) * IN_DIM + il];
#pragma unroll
    for (int q = 0; q < 4; ++q)
      glds16(bgbase + (size_t)q * 32 * KDIM,
             (char*)&Bsh[0][0] + wave * 1024 + q * 4096);
    glds16(xg + 4, (char*)Xsh + 1 * 1024);
#pragma unroll
    for (int q = 0; q < 4; ++q)
      glds16(bgbase + (size_t)BK + (size_t)q * 32 * KDIM,
             (char*)&Bsh[0][0] + BTILE + wave * 1024 + q * 4096);
    glds16(xg + 8, (char*)Xsh + 2 * 1024);
    if (astage) {
      unsigned d[8];
      spline_row(x0v, d);
      *(int4*)(abase + aw0) = *(const int4*)&d[0];
      *(int4*)(abase + aw1) = *(const int4*)&d[4];
    }
    asm volatile("s_waitcnt vmcnt(5) lgkmcnt(0)" ::: "memory");
    __builtin_amdgcn_sched_barrier(0);
    __builtin_amdgcn_s_barrier();
  }

  for (int s = 0; s < STEPS; ++s) {
    const int cur = s & 1;
    // 1. B DMA for tile s+2 (clamped dummy into dead slot at tail)
    {
      const int tf = (s + 2 < STEPS) ? s + 2 : STEPS - 1;
      char* bd = (char*)&Bsh[0][0] + ((s + 2) % 3) * BTILE + wave * 1024;
#pragma unroll
      for (int q = 0; q < 4; ++q)
        glds16(bgbase + (size_t)tf * BK + (size_t)q * 32 * KDIM, bd + q * 4096);
    }
    // 2. x DMA for group s+3 (clamped; all waves, identical bytes)
    {
      const int xf = (s + 3 < STEPS) ? s + 3 : STEPS - 1;
      glds16(xg + 4 * xf, (char*)Xsh + ((s + 3) % 3) * 1024);
    }
    // 3. MFMA phase on tile s (slot s%3), A[cur]
    const char* Ac = (const char*)&Ash[0][0] + cur * ABUF;
    const char* Bc = (const char*)&Bsh[0][0] + (s % 3) * BTILE;
    __builtin_amdgcn_s_setprio(1);
#pragma unroll
    for (int kc = 0; kc < 2; ++kc) {
      short8 af[2], bfr[2];
#pragma unroll
      for (int f = 0; f < 2; ++f) af[f] = *(const short8*)(Ac + (aoff[f] ^ (kc << 6)));
#pragma unroll
      for (int f = 0; f < 2; ++f) bfr[f] = *(const short8*)(Bc + (boff[f] ^ (kc << 6)));
#pragma unroll
      for (int mf = 0; mf < 2; ++mf)
#pragma unroll
        for (int nf = 0; nf < 2; ++nf)
          acc[mf][nf] = __builtin_amdgcn_mfma_f32_16x16x32_bf16(af[mf], bfr[nf], acc[mf][nf], 0, 0, 0);
    }
    __builtin_amdgcn_s_setprio(0);
    // 4. spline-stage A[s+1] from x[s+1] (LDS slot (s+1)%3, retired last step)
    if (astage && s + 1 < STEPS) {
      float xv = Xsh[((s + 1) % 3) * 256 + 4 * r + il];
      unsigned d[8];
      spline_row(xv, d);
      char* an = abase + (1 - cur) * ABUF;
      *(int4*)(an + aw0) = *(const int4*)&d[0];
      *(int4*)(an + aw1) = *(const int4*)&d[4];
    }
    // 5. pre-barrier counted wait: retire T(s+1)(4)+X(s+2); T(s+2)+X(s+3) stay
    //    in flight across the barrier. lgkmcnt(0) makes A-writes visible.
    asm volatile("s_waitcnt vmcnt(5) lgkmcnt(0)" ::: "memory");
    __builtin_amdgcn_sched_barrier(0);
    __builtin_amdgcn_s_barrier();
  }
  asm volatile("s_waitcnt vmcnt(0) lgkmcnt(0)" ::: "memory");  // drain tail dummies

  // epilogue: direct coalesced stores (each output element written exactly once)
#pragma unroll
  for (int mf = 0; mf < 2; ++mf)
#pragma unroll
    for (int nf = 0; nf < 2; ++nf)
#pragma unroll
      for (int q = 0; q < 4; ++q) {
        int row = mb + mf * 16 + ((lane >> 4) << 2) + q;
        int col = ob + wn * 32 + nf * 16 + (lane & 15);
        out[(size_t)row * OUT_DIM + col] = acc[mf][nf][q];
      }
}

extern "C" void kernel_launch(void* const* d_in, const int* in_sizes, int n_in,
                              void* d_out, int out_size, void* d_ws, size_t ws_size,
                              hipStream_t stream) {
  const float* x     = (const float*)d_in[0];   // (4,2048,256) f32
  const float* coeff = (const float*)d_in[1];   // (8,13) f32
  const float* gw    = (const float*)d_in[2];   // (256,256,8) f32
  float* out = (float*)d_out;                   // (4,2048,256) f32
  unsigned short* BmT = (unsigned short*)d_ws;  // 256 x 4096 bf16 = 2 MB

  kan_prep<<<dim3(16, 16), dim3(256), 0, stream>>>(coeff, gw, BmT);
  dim3 grid(8192 / TM, OUT_DIM / TN);
  kan_gemm<<<grid, dim3(256), 0, stream>>>(x, BmT, out);
}

// Round 9
// 122.302 us; speedup vs baseline: 1.0373x; 1.0373x over previous
//
#include <hip/hip_runtime.h>

typedef __attribute__((ext_vector_type(8))) short short8;
typedef __attribute__((ext_vector_type(4))) float f32x4;

#define IN_DIM 256
#define OUT_DIM 256
#define K2 2048               // k = i*8 + e  (coeff folded into A-side polynomial)
#define TM 32
#define TN 128
#define NSLICE 64             // 64 kc-slices of 32 k (= 4 i) each

__device__ __forceinline__ unsigned short f2bf(float f) {
  union { float f; unsigned int u; } v; v.f = f;
  unsigned int r = v.u + 0x7fffu + ((v.u >> 16) & 1u);  // RNE
  return (unsigned short)(r >> 16);
}

// --- prep: G2[o][i*8+e] = softmax(gating[i,o,:])[e]  (bf16, 1 MB workspace)
__global__ __launch_bounds__(256) void kan_prep(const float* __restrict__ gw,
                                                unsigned short* __restrict__ G2) {
  const int t = threadIdx.x;
  const int il = t & 15, ol = t >> 4;          // il fastest -> coalesced stores
  const int i = blockIdx.y * 16 + il;
  const int o = blockIdx.x * 16 + ol;
  const float* g = gw + (size_t)(i * OUT_DIM + o) * 8;
  float4 g0 = *(const float4*)g;
  float4 g1 = *(const float4*)(g + 4);
  float ge[8] = {g0.x, g0.y, g0.z, g0.w, g1.x, g1.y, g1.z, g1.w};
  float mx = ge[0];
#pragma unroll
  for (int e = 1; e < 8; ++e) mx = fmaxf(mx, ge[e]);
  float p[8]; float s = 0.f;
#pragma unroll
  for (int e = 0; e < 8; ++e) { p[e] = __expf(ge[e] - mx); s += p[e]; }
  const float inv = 1.0f / s;
  unsigned w[4];
#pragma unroll
  for (int q = 0; q < 4; ++q)
    w[q] = (unsigned)f2bf(p[2 * q] * inv) | ((unsigned)f2bf(p[2 * q + 1] * inv) << 16);
  *(int4*)(G2 + (size_t)o * K2 + i * 8) = *(const int4*)w;
}

// per-lane A-fragment eval: cubic Horner over 8 experts from the LDS poly table.
// Produces exactly the 8 bf16 elements lane l holds of the MFMA A operand.
__device__ __forceinline__ short8 evalA(float xv, const float* __restrict__ PT) {
  float xc = fminf(fmaxf(xv, -1.0f), 1.0f - 1e-6f);
  float u = (xc + 1.0f) * 5.0f;                // h = 0.2, u in [0, 10)
  int c = (int)u;
  c = c > 9 ? 9 : c;
  float tt = u - (float)c;
  const float* p = PT + c * 36;                // stride 36 floats (144 B) spreads banks
  float pv[8];
#pragma unroll
  for (int e = 0; e < 8; ++e) {
    f32x4 a = *(const f32x4*)(p + e * 4);      // (a0,a1,a2,a3), 16 B aligned
    pv[e] = fmaf(fmaf(fmaf(a[3], tt, a[2]), tt, a[1]), tt, a[0]);
  }
  union { unsigned w[4]; short8 s; } r;
#pragma unroll
  for (int q = 0; q < 4; ++q) {
    unsigned lo = (__float_as_uint(pv[2 * q]) + 0x8000u) >> 16;       // round-half-up
    unsigned hi = (__float_as_uint(pv[2 * q + 1]) + 0x8000u) & 0xFFFF0000u;
    r.w[q] = lo | hi;
  }
  return r.s;
}

// --- fused GEMM, NO LDS staging, NO barriers in the K-loop:
// out[m][o] = sum_k P[m][k] * G2[o][k], k = i*8+e, K2 = 2048.
// A-frags computed in-register per lane (Horner over a 1.4 KB LDS poly table);
// B-frags loaded directly from L2-resident G2 (1 MB) as 16 B/lane dwordx4.
// TM=32 x TN=128, 4 waves (1M x 4N), grid (256,2)=512 blocks, direct stores.
__global__ __launch_bounds__(256, 2) void kan_gemm(const float* __restrict__ x,
                                                   const float* __restrict__ coeff,
                                                   const unsigned short* __restrict__ G2,
                                                   float* __restrict__ out) {
  __shared__ __align__(16) float PT[360];      // [c:10][e:8][p:4], c-stride 36

  const int t = threadIdx.x;
  // build poly table from coeff (B-spline pieces expanded in local t):
  //   a0=(C0+4C1+C2)/6, a1=(C2-C0)/2, a2=(C0-2C1+C2)/2, a3=(C3-C0+3(C1-C2))/6
  if (t < 80) {
    const int c = t >> 3, e = t & 7;
    const float C0 = coeff[e * 13 + c],     C1 = coeff[e * 13 + c + 1];
    const float C2 = coeff[e * 13 + c + 2], C3 = coeff[e * 13 + c + 3];
    float* p = &PT[c * 36 + e * 4];
    p[0] = (C0 + 4.0f * C1 + C2) * (1.0f / 6.0f);
    p[1] = (C2 - C0) * 0.5f;
    p[2] = (C0 - 2.0f * C1 + C2) * 0.5f;
    p[3] = (C3 - C0 + 3.0f * (C1 - C2)) * (1.0f / 6.0f);
  }
  __syncthreads();                             // the only block-wide barrier

  const int lane = t & 63;
  const int wn = t >> 6;                       // 4 waves: 1 M x 4 N, each 32x32
  const int mb = blockIdx.x * TM;
  const int ob = blockIdx.y * TN;
  const int rl = lane & 15;                    // fragment row/col within 16
  const int iq = lane >> 4;                    // which of the slice's 4 i this lane owns

  // x: value for slice s at xp[4s]; block strip is 32 KB (L1-resident)
  const float* xp0 = x + (size_t)(mb + rl) * IN_DIM + iq;
  const float* xp1 = xp0 + 16 * IN_DIM;
  // B: lane reads 16 B of G2 row (o), advancing 64 B per slice
  const unsigned short* bp0 = G2 + (size_t)(ob + wn * 32 + rl) * K2 + iq * 8;
  const unsigned short* bp1 = bp0 + 16 * K2;

  f32x4 acc[2][2];
#pragma unroll
  for (int a = 0; a < 2; ++a)
#pragma unroll
    for (int b = 0; b < 2; ++b) acc[a][b] = (f32x4){0.f, 0.f, 0.f, 0.f};

#pragma unroll 2
  for (int s = 0; s < NSLICE; ++s) {
    const float x0 = xp0[s * 4];
    const float x1 = xp1[s * 4];
    const short8 b0 = *(const short8*)(bp0 + s * 32);
    const short8 b1 = *(const short8*)(bp1 + s * 32);
    const short8 a0 = evalA(x0, PT);
    const short8 a1 = evalA(x1, PT);
    acc[0][0] = __builtin_amdgcn_mfma_f32_16x16x32_bf16(a0, b0, acc[0][0], 0, 0, 0);
    acc[0][1] = __builtin_amdgcn_mfma_f32_16x16x32_bf16(a0, b1, acc[0][1], 0, 0, 0);
    acc[1][0] = __builtin_amdgcn_mfma_f32_16x16x32_bf16(a1, b0, acc[1][0], 0, 0, 0);
    acc[1][1] = __builtin_amdgcn_mfma_f32_16x16x32_bf16(a1, b1, acc[1][1], 0, 0, 0);
  }

  // epilogue: direct coalesced stores (each output element written exactly once)
#pragma unroll
  for (int mf = 0; mf < 2; ++mf)
#pragma unroll
    for (int nf = 0; nf < 2; ++nf)
#pragma unroll
      for (int q = 0; q < 4; ++q) {
        int row = mb + mf * 16 + (iq << 2) + q;
        int col = ob + wn * 32 + nf * 16 + rl;
        out[(size_t)row * OUT_DIM + col] = acc[mf][nf][q];
      }
}

extern "C" void kernel_launch(void* const* d_in, const int* in_sizes, int n_in,
                              void* d_out, int out_size, void* d_ws, size_t ws_size,
                              hipStream_t stream) {
  const float* x     = (const float*)d_in[0];   // (4,2048,256) f32
  const float* coeff = (const float*)d_in[1];   // (8,13) f32
  const float* gw    = (const float*)d_in[2];   // (256,256,8) f32
  float* out = (float*)d_out;                   // (4,2048,256) f32
  unsigned short* G2 = (unsigned short*)d_ws;   // 256 x 2048 bf16 = 1 MB

  kan_prep<<<dim3(16, 16), dim3(256), 0, stream>>>(gw, G2);
  dim3 grid(8192 / TM, OUT_DIM / TN);
  kan_gemm<<<grid, dim3(256), 0, stream>>>(x, coeff, G2, out);
}